// Round 3
// baseline (249.842 us; speedup 1.0000x reference)
//
#include <hip/hip_runtime.h>
#include <hip/hip_bf16.h>
#include <cstdint>

#define T_  4096
#define H_  1024
#define E_  16
#define MI_ 512
#define SI_ 2048
#define TK_ 8192   // T_ * K(=2)

typedef __bf16 bf16;
typedef bf16  bf16x8 __attribute__((ext_vector_type(8)));
typedef bf16  bf16x4 __attribute__((ext_vector_type(4)));
typedef float f32x4  __attribute__((ext_vector_type(4)));

// async global->LDS, 16B per lane. LDS dest = wave-uniform base + lane*16.
__device__ __forceinline__ void gload16(const bf16* g, bf16* lds) {
    __builtin_amdgcn_global_load_lds(
        (const __attribute__((address_space(1))) void*)(uintptr_t)(const void*)g,
        (__attribute__((address_space(3))) void*)(uintptr_t)(void*)lds,
        16, 0, 0);
}

// ---------------- fp32 -> bf16 flat convert (vectorized) ----------------
__global__ void k_convert(const float* __restrict__ src, bf16* __restrict__ dst, int n4) {
    int i = blockIdx.x * blockDim.x + threadIdx.x;
    if (i < n4) {
        float4 v = reinterpret_cast<const float4*>(src)[i];
        bf16x4 o;
        o[0] = (bf16)v.x; o[1] = (bf16)v.y; o[2] = (bf16)v.z; o[3] = (bf16)v.w;
        reinterpret_cast<bf16x4*>(dst)[i] = o;
    }
}

// ---------------- fp32 [R][C] -> bf16 [C][R] transpose (per z-slice) ----------------
__global__ void k_transpose(const float* __restrict__ src, bf16* __restrict__ dst, int R, int C) {
    __shared__ float tile[32][33];
    size_t zoff = (size_t)blockIdx.z * (size_t)R * (size_t)C;
    src += zoff; dst += zoff;
    int c  = blockIdx.x * 32 + threadIdx.x;
    #pragma unroll
    for (int i = 0; i < 4; i++) {
        int r = blockIdx.y * 32 + threadIdx.y + i * 8;
        tile[threadIdx.y + i * 8][threadIdx.x] = src[(size_t)r * C + c];
    }
    __syncthreads();
    int rr = blockIdx.y * 32 + threadIdx.x;   // original row -> new col
    #pragma unroll
    for (int i = 0; i < 4; i++) {
        int cc = blockIdx.x * 32 + threadIdx.y + i * 8;  // original col -> new row
        dst[(size_t)cc * R + rr] = (bf16)tile[threadIdx.x][threadIdx.y + i * 8];
    }
}

// ---------------- router: logits (fp32), top-2, shared gate scalar. NO atomics. ----------------
__global__ __launch_bounds__(256) void k_router(
    const float* __restrict__ x, const float* __restrict__ rw,
    const float* __restrict__ segw, float* __restrict__ logits_out,
    int* __restrict__ top_i, float* __restrict__ top_w,
    float* __restrict__ gate_scalar)
{
    int wid = threadIdx.x >> 6, lane = threadIdx.x & 63;
    int t = blockIdx.x * 4 + wid;
    const float* xr = x + (size_t)t * H_;
    float acc[E_];
    #pragma unroll
    for (int e = 0; e < E_; e++) acc[e] = 0.f;
    float accg = 0.f;
    for (int j = 0; j < H_ / 64; j++) {
        int h = j * 64 + lane;
        float xv = xr[h];
        const float4* wrow = reinterpret_cast<const float4*>(rw + (size_t)h * E_);
        #pragma unroll
        for (int q = 0; q < 4; q++) {
            float4 w4 = wrow[q];
            acc[q*4+0] += xv * w4.x; acc[q*4+1] += xv * w4.y;
            acc[q*4+2] += xv * w4.z; acc[q*4+3] += xv * w4.w;
        }
        accg += xv * segw[h];
    }
    #pragma unroll
    for (int off = 32; off >= 1; off >>= 1) {
        #pragma unroll
        for (int e = 0; e < E_; e++) acc[e] += __shfl_xor(acc[e], off);
        accg += __shfl_xor(accg, off);
    }
    if (lane == 0) {
        float* lo = logits_out + (size_t)t * E_;
        #pragma unroll
        for (int e = 0; e < E_; e++) lo[e] = acc[e];
        int i0 = 0; float l0 = acc[0];
        #pragma unroll
        for (int e = 1; e < E_; e++) if (acc[e] > l0) { l0 = acc[e]; i0 = e; }
        int i1 = -1; float l1 = -1e30f;
        #pragma unroll
        for (int e = 0; e < E_; e++) if (e != i0 && acc[e] > l1) { l1 = acc[e]; i1 = e; }
        float w0 = 1.f / (1.f + expf(l1 - l0));   // p0/(p0+p1)
        top_i[t*2] = i0; top_i[t*2+1] = i1;
        top_w[t*2] = w0; top_w[t*2+1] = 1.f - w0;
        gate_scalar[t] = 1.f / (1.f + expf(-accg));
    }
}

// ---------------- counts + offsets from top_i, single block, no global atomics ----------------
__global__ __launch_bounds__(256) void k_count(const int* __restrict__ top_i, int* __restrict__ offsets) {
    __shared__ int hist[256][17];
    int tid = threadIdx.x;
    #pragma unroll
    for (int e = 0; e < E_; e++) hist[tid][e] = 0;
    __syncthreads();
    const int* mine = top_i + tid * 32;
    #pragma unroll
    for (int j = 0; j < 32; j++) hist[tid][mine[j]]++;
    __syncthreads();
    if (tid < E_) {
        int s = 0;
        for (int r = 0; r < 256; r++) s += hist[r][tid];
        hist[0][tid] = s;
    }
    __syncthreads();
    if (tid == 0) {
        int s = 0;
        for (int e = 0; e < E_; e++) { offsets[e] = s; s += hist[0][e]; }
        offsets[E_] = s;
    }
}

// ---------------- deterministic slot assignment by rank (prefix scan), one block per expert ----------------
__global__ __launch_bounds__(256) void k_fillscan(
    const int* __restrict__ top_i, const int* __restrict__ offsets,
    int* __restrict__ slot_token, int* __restrict__ slot_pos)
{
    int e = blockIdx.x;
    int tid = threadIdx.x;
    int lane = tid & 63, w = tid >> 6;
    __shared__ int wsum[4];

    int t0 = tid * 16;
    unsigned f0 = 0, f1 = 0;
    int c = 0;
    #pragma unroll
    for (int j = 0; j < 16; j++) {
        int t = t0 + j;
        int a = top_i[t*2], b = top_i[t*2+1];
        if (a == e)      { f0 |= 1u << j; c++; }
        else if (b == e) { f1 |= 1u << j; c++; }
    }
    int incl = c;
    #pragma unroll
    for (int off = 1; off < 64; off <<= 1) {
        int v = __shfl_up(incl, off);
        if (lane >= off) incl += v;
    }
    if (lane == 63) wsum[w] = incl;
    __syncthreads();
    int wbase = 0;
    for (int i = 0; i < w; i++) wbase += wsum[i];
    int pos = offsets[e] + wbase + (incl - c);
    #pragma unroll
    for (int j = 0; j < 16; j++) {
        int t = t0 + j;
        if ((f0 >> j) & 1u)      { slot_token[pos] = t; slot_pos[t*2]   = pos; pos++; }
        else if ((f1 >> j) & 1u) { slot_token[pos] = t; slot_pos[t*2+1] = pos; pos++; }
    }
}

// ---------------- unified m97-style GEMM ----------------
// MODE 0: expert gate/up + silu-mul -> hiddenE (bf16), A = xb gathered via slot_token, K=1024
// MODE 1: shared gate/up + silu-mul -> sh_hid (bf16), K=1024
// MODE 2: expert down -> eo (bf16), A = hiddenE (slot rows), K=512
// MODE 3: shared down -> d_out (f32, * gate_s), A = sh_hid, K=2048
// Tile: 128 rows x (GU: 64 paired cols / DOWN: 128 cols), BK=32, 256 threads.
// B stored [N][K] row-major; B-tile = [B0 rows 0..63 ; B1 rows 0..63].
template<int MODE, int KDIM>
__global__ __launch_bounds__(256) void k_gemm(
    const bf16* __restrict__ A, const bf16* __restrict__ Bbase, const bf16* __restrict__ Bbase2,
    const int* __restrict__ slot_token, const int* __restrict__ offsets,
    const float* __restrict__ gate_s,
    bf16* __restrict__ out_bf, float* __restrict__ out_f32)
{
    constexpr bool EXPERT = (MODE == 0 || MODE == 2);
    constexpr bool GU     = (MODE <= 1);
    int e = blockIdx.z;
    int base = EXPERT ? offsets[e] : 0;
    int cnt  = EXPERT ? offsets[e+1] - base : T_;
    int mt = blockIdx.y, nt = blockIdx.x;
    if (mt * 128 >= cnt) return;

    const bf16 *B0, *B1;
    if (MODE == 0) {
        const bf16* wb = Bbase + (size_t)e * (2 * MI_) * H_;
        B0 = wb + (size_t)(nt * 64) * KDIM;
        B1 = wb + (size_t)(MI_ + nt * 64) * KDIM;
    } else if (MODE == 1) {
        B0 = Bbase  + (size_t)(nt * 64) * KDIM;
        B1 = Bbase2 + (size_t)(nt * 64) * KDIM;
    } else if (MODE == 2) {
        const bf16* wb = Bbase + (size_t)e * H_ * MI_;
        B0 = wb + (size_t)(nt * 128) * KDIM;
        B1 = B0 + (size_t)64 * KDIM;
    } else {
        B0 = Bbase + (size_t)(nt * 128) * KDIM;
        B1 = B0 + (size_t)64 * KDIM;
    }

    __shared__ __align__(16) bf16 As[128 * 32];
    __shared__ __align__(16) bf16 Bs[128 * 32];

    int tid = threadIdx.x, w = tid >> 6, l = tid & 63;
    int srow = l >> 2;            // 0..15
    int scol = (l & 3) * 8;       // bf16 elems (16B chunks)

    // per-lane global source pointers (fixed across k-loop)
    const bf16* asrc[2];
    const bf16* bsrc[2];
    #pragma unroll
    for (int i = 0; i < 2; i++) {
        int r = i * 64 + w * 16 + srow;         // row within 128-tile
        if (MODE == 0) {
            int s = mt * 128 + r; if (s >= cnt) s = cnt - 1;
            asrc[i] = A + (size_t)slot_token[base + s] * KDIM + scol;
        } else if (MODE == 2) {
            int s = mt * 128 + r; if (s >= cnt) s = cnt - 1;
            asrc[i] = A + (size_t)(base + s) * KDIM + scol;
        } else {
            asrc[i] = A + (size_t)(mt * 128 + r) * KDIM + scol;
        }
        bsrc[i] = (r < 64 ? B0 + (size_t)r * KDIM : B1 + (size_t)(r - 64) * KDIM) + scol;
    }
    // wave-uniform LDS staging bases (HW adds lane*16B)
    bf16* a_dst0 = &As[(size_t)(0  + w * 16) * 32];
    bf16* a_dst1 = &As[(size_t)(64 + w * 16) * 32];
    bf16* b_dst0 = &Bs[(size_t)(0  + w * 16) * 32];
    bf16* b_dst1 = &Bs[(size_t)(64 + w * 16) * 32];

    int lr = l & 15, kq = l >> 4;
    f32x4 acc[2][8];
    #pragma unroll
    for (int mi = 0; mi < 2; mi++)
        #pragma unroll
        for (int ni = 0; ni < 8; ni++) acc[mi][ni] = (f32x4){0.f, 0.f, 0.f, 0.f};

    for (int k0 = 0; k0 < KDIM; k0 += 32) {
        __syncthreads();
        gload16(asrc[0] + k0, a_dst0);
        gload16(asrc[1] + k0, a_dst1);
        gload16(bsrc[0] + k0, b_dst0);
        gload16(bsrc[1] + k0, b_dst1);
        asm volatile("s_waitcnt vmcnt(0)" ::: "memory");
        __syncthreads();
        bf16x8 af[2], bfr[8];
        #pragma unroll
        for (int mi = 0; mi < 2; mi++)
            af[mi] = *reinterpret_cast<const bf16x8*>(&As[(w * 32 + mi * 16 + lr) * 32 + kq * 8]);
        #pragma unroll
        for (int ni = 0; ni < 8; ni++)
            bfr[ni] = *reinterpret_cast<const bf16x8*>(&Bs[(ni * 16 + lr) * 32 + kq * 8]);
        #pragma unroll
        for (int mi = 0; mi < 2; mi++)
            #pragma unroll
            for (int ni = 0; ni < 8; ni++)
                acc[mi][ni] = __builtin_amdgcn_mfma_f32_16x16x32_bf16(af[mi], bfr[ni], acc[mi][ni], 0, 0, 0);
    }

    // epilogue: D row = A_row_base + kq*4 + r, col = B_row_base + lr (m89-verified)
    #pragma unroll
    for (int mi = 0; mi < 2; mi++)
        #pragma unroll
        for (int ni = 0; ni < (GU ? 4 : 8); ni++)
            #pragma unroll
            for (int r = 0; r < 4; r++) {
                int row = mt * 128 + w * 32 + mi * 16 + kq * 4 + r;
                if (row < cnt) {
                    if (GU) {
                        constexpr int NOUT = (MODE == 0) ? MI_ : SI_;
                        int col = nt * 64 + ni * 16 + lr;
                        float g = acc[mi][ni][r], u = acc[mi][ni + 4][r];
                        float hv = u * (g / (1.f + expf(-g)));
                        out_bf[(size_t)(base + row) * NOUT + col] = (bf16)hv;
                    } else {
                        int col = nt * 128 + ni * 16 + lr;
                        float v = acc[mi][ni][r];
                        if (MODE == 2) out_bf[(size_t)(base + row) * H_ + col] = (bf16)v;
                        else           out_f32[(size_t)row * H_ + col] = gate_s[row] * v;
                    }
                }
            }
}

// ---------------- combine: out += w0*eo[s0] + w1*eo[s1] ----------------
__global__ void k_combine(float* __restrict__ out, const bf16* __restrict__ eo,
                          const int* __restrict__ slot_pos, const float* __restrict__ top_w)
{
    int i = blockIdx.x * blockDim.x + threadIdx.x;
    int t = i >> 8;
    int q = (i & 255) * 4;
    int s0 = slot_pos[t*2], s1 = slot_pos[t*2+1];
    float w0 = top_w[t*2], w1 = top_w[t*2+1];
    bf16x4 e0 = *reinterpret_cast<const bf16x4*>(eo + (size_t)s0 * H_ + q);
    bf16x4 e1 = *reinterpret_cast<const bf16x4*>(eo + (size_t)s1 * H_ + q);
    float4* op = reinterpret_cast<float4*>(out) + i;
    float4 so = *op;
    float4 r;
    r.x = so.x + w0 * (float)e0[0] + w1 * (float)e1[0];
    r.y = so.y + w0 * (float)e0[1] + w1 * (float)e1[1];
    r.z = so.z + w0 * (float)e0[2] + w1 * (float)e1[2];
    r.w = so.w + w0 * (float)e0[3] + w1 * (float)e1[3];
    *op = r;
}

extern "C" void kernel_launch(void* const* d_in, const int* in_sizes, int n_in,
                              void* d_out, int out_size, void* d_ws, size_t ws_size,
                              hipStream_t stream) {
    const float* x    = (const float*)d_in[0];
    const float* rw   = (const float*)d_in[1];
    const float* wgu  = (const float*)d_in[2];
    const float* wdn  = (const float*)d_in[3];
    const float* wsg  = (const float*)d_in[4];
    const float* wsu  = (const float*)d_in[5];
    const float* wsd  = (const float*)d_in[6];
    const float* segw = (const float*)d_in[7];
    float* out    = (float*)d_out;
    float* logits = (float*)d_out + (size_t)T_ * H_;

    char* p = (char*)d_ws;
    bf16* xb      = (bf16*)p;  p += (size_t)T_ * H_ * 2;
    bf16* w_guT   = (bf16*)p;  p += (size_t)E_ * H_ * (2*MI_) * 2;
    bf16* w_dnT   = (bf16*)p;  p += (size_t)E_ * MI_ * H_ * 2;
    bf16* w_sgT   = (bf16*)p;  p += (size_t)H_ * SI_ * 2;
    bf16* w_suT   = (bf16*)p;  p += (size_t)H_ * SI_ * 2;
    bf16* w_sdT   = (bf16*)p;  p += (size_t)SI_ * H_ * 2;
    bf16* hiddenE = (bf16*)p;  p += (size_t)TK_ * MI_ * 2;
    bf16* sh_hid  = (bf16*)p;  p += (size_t)T_ * SI_ * 2;
    bf16* eo      = (bf16*)p;  p += (size_t)TK_ * H_ * 2;
    float* gate_s = (float*)p; p += (size_t)T_ * 4;
    int*  top_i   = (int*)p;   p += (size_t)T_ * 2 * 4;
    float* top_w  = (float*)p; p += (size_t)T_ * 2 * 4;
    int*  slot_pos= (int*)p;   p += (size_t)T_ * 2 * 4;
    int*  slot_tok= (int*)p;   p += (size_t)TK_ * 4;
    int*  offsets = (int*)p;   p += 17 * 4;

    // conversions + transposes
    k_convert<<<dim3(T_*H_/4/256), 256, 0, stream>>>(x, xb, T_*H_/4);
    k_transpose<<<dim3(32, 32, 16), dim3(32, 8), 0, stream>>>(wgu, w_guT, 1024, 1024);
    k_transpose<<<dim3(32, 16, 16), dim3(32, 8), 0, stream>>>(wdn, w_dnT, 512, 1024);
    k_transpose<<<dim3(64, 32, 1),  dim3(32, 8), 0, stream>>>(wsg, w_sgT, 1024, 2048);
    k_transpose<<<dim3(64, 32, 1),  dim3(32, 8), 0, stream>>>(wsu, w_suT, 1024, 2048);
    k_transpose<<<dim3(32, 64, 1),  dim3(32, 8), 0, stream>>>(wsd, w_sdT, 2048, 1024);

    // routing (atomic-free)
    k_router<<<dim3(T_/4), 256, 0, stream>>>(x, rw, segw, logits, top_i, top_w, gate_s);
    k_count<<<dim3(1), 256, 0, stream>>>(top_i, offsets);
    k_fillscan<<<dim3(E_), 256, 0, stream>>>(top_i, offsets, slot_tok, slot_pos);

    // expert path
    k_gemm<0,1024><<<dim3(MI_/64, 32, E_), 256, 0, stream>>>(xb, w_guT, nullptr, slot_tok, offsets, nullptr, hiddenE, nullptr);
    k_gemm<2, 512><<<dim3(H_/128, 32, E_), 256, 0, stream>>>(hiddenE, w_dnT, nullptr, nullptr, offsets, nullptr, eo, nullptr);

    // shared expert path
    k_gemm<1,1024><<<dim3(SI_/64, 32, 1), 256, 0, stream>>>(xb, w_sgT, w_suT, nullptr, offsets, nullptr, sh_hid, nullptr);
    k_gemm<3,2048><<<dim3(H_/128, 32, 1), 256, 0, stream>>>(sh_hid, w_sdT, nullptr, nullptr, offsets, gate_s, nullptr, out);

    // combine expert contributions into d_out
    k_combine<<<dim3(T_*256/256), 256, 0, stream>>>(out, eo, slot_pos, top_w);
}